// Round 7
// baseline (234.940 us; speedup 1.0000x reference)
//
#include <hip/hip_runtime.h>
#include <hip/hip_bf16.h>

// ---------------------------------------------------------------------------
// WindowAttention: B=32 RES=56 C=128 HEADS=4 HD=32 WS=7 NW=8 NQ=64 WA=49
// 128 keys/window (64 gathered full-res + 64 x1-level). fp32 I/O, bf16 MFMA.
// Round-6 verified structure. Delta this round: k_qkv/k_proj use SWAPPED
// MFMA operands (mfma(W,X) -> C^T): identical LDS reads, but each thread's
// C-fragment is ONE row x 32 consecutive channels -> epilogue is 8 vector
// stores (b64 bf16 / b128 fp32) instead of 32 scalar stores, and the
// window-index div chain runs once per thread instead of 4x.
// Buffer plan:
//   d_out: per-window interleaved — q (bf16, first 12544B of each 25088B
//   window slot) -> k_attn preloads Q to regs, then writes fp32 attention
//   output over the full slot (block-local alias) -> k_proj in-place.
//   d_ws 56.75MB: k0,v0,k1,v1 (bf16) + rpb (bf16 thread-linear, pre-scaled
//   sqrt(32)) + wq_bf16 + wp_bf16.
// ---------------------------------------------------------------------------

typedef __bf16 bf16_t;
typedef __bf16 bf16x8 __attribute__((ext_vector_type(8)));
typedef __bf16 bf16x4 __attribute__((ext_vector_type(4)));
typedef float f32x4 __attribute__((ext_vector_type(4)));

static __device__ __forceinline__ f32x4 mfma_bf16(bf16x8 a, bf16x8 b, f32x4 c) {
  return __builtin_amdgcn_mfma_f32_16x16x32_bf16(a, b, c, 0, 0, 0);
}

static __device__ __forceinline__ bf16x8 cvt8(const float* __restrict__ p) {
  float4 a = *(const float4*)p;
  float4 b = *(const float4*)(p + 4);
  bf16x8 r;
  r[0] = (bf16_t)a.x; r[1] = (bf16_t)a.y; r[2] = (bf16_t)a.z; r[3] = (bf16_t)a.w;
  r[4] = (bf16_t)b.x; r[5] = (bf16_t)b.y; r[6] = (bf16_t)b.z; r[7] = (bf16_t)b.w;
  return r;
}

#define NB 32
#define RES 56
#define CH 128
#define NW 8
#define NQ 64
#define WA 49
#define X0_ROWS (NB * RES * RES)       // 100352
#define SCALE 0.17677669529663687f     // 32^-0.5
#define SQRT32 5.656854249492381f
#define KE 0.25503164508761f           // SCALE * log2(e)

// ---------------------------------------------------------------------------
// K0: weight pre-convert: qkv_w (49152 f32) + proj_w (16384 f32) -> bf16.
// grid 32 x 256, 8 elems/thread.
// ---------------------------------------------------------------------------
__global__ __launch_bounds__(256) void k_prep(
    const float* __restrict__ qw, const float* __restrict__ pw,
    bf16_t* __restrict__ wq, bf16_t* __restrict__ wp) {
  int i = (blockIdx.x * 256 + threadIdx.x) * 8;
  if (i < 49152) {
    *(bf16x8*)&wq[i] = cvt8(qw + i);
  } else {
    int j = i - 49152;
    *(bf16x8*)&wp[j] = cvt8(pw + j);
  }
}

// ---------------------------------------------------------------------------
// K1: qkv GEMM, A staged once, cb=q/k/v looped in-block. grid 1600 x 256.
// B staged from pre-converted bf16 weights. MFMA operands SWAPPED: thread
// owns one output row (wid*16+lr), channels nt*16+lkg*4+{0..3} -> b64 stores.
// ---------------------------------------------------------------------------
__global__ __launch_bounds__(256) void k_qkv(
    const float* __restrict__ x0, const float* __restrict__ x1,
    const bf16_t* __restrict__ w, const float* __restrict__ bias,
    bf16_t* __restrict__ qout,          // d_out, interleaved windows
    bf16_t* __restrict__ k0, bf16_t* __restrict__ v0,
    bf16_t* __restrict__ k1, bf16_t* __restrict__ v1) {
  __shared__ __align__(16) bf16_t Asm[64][136];
  __shared__ __align__(16) bf16_t Bsm[128][136];
  const int rb = blockIdx.x;           // 0..1599 (>=1568: x1 rows)
  const int tid = threadIdx.x;
  const size_t row0 = (size_t)rb * 64;
  const bool is_x0 = (rb < 1568);
  const int b_ = rb / 49;              // 3136 = 49*64: block never crosses batch
  const int pix0 = (rb - b_ * 49) * 64;
  const int i1base = (rb - 1568) * 64;

  const float* src = is_x0 ? (x0 + row0 * CH)
                           : (x1 + (row0 - X0_ROWS) * CH);
#pragma unroll
  for (int i = 0; i < 4; ++i) {        // A: 64x128
    int uid = tid + 256 * i;
    int r = uid >> 4, cs = uid & 15;
    *(bf16x8*)&Asm[r][cs * 8] = cvt8(src + (size_t)r * CH + cs * 8);
  }

  const int wid = tid >> 6, l = tid & 63;
  const int lr = l & 15, lkg = l >> 4, lk = lkg * 8;
  const int local = wid * 16 + lr;     // this thread's output row

  for (int cb = 0; cb < 3; ++cb) {
    const bf16_t* wsrc = w + (size_t)cb * 128 * CH;
#pragma unroll
    for (int i = 0; i < 8; ++i) {      // B: 128x128 (bf16 copy, no cvt)
      int uid = tid + 256 * i;
      int r = uid >> 4, cs = uid & 15;
      *(uint4*)&Bsm[r][cs * 8] = *(const uint4*)(wsrc + (size_t)r * CH + cs * 8);
    }
    __syncthreads();

    f32x4 zero = {0.f, 0.f, 0.f, 0.f};
    f32x4 acc[8];
#pragma unroll
    for (int nt = 0; nt < 8; ++nt) acc[nt] = zero;
#pragma unroll
    for (int ks = 0; ks < 4; ++ks) {
      bf16x8 a = *(const bf16x8*)&Asm[wid * 16 + lr][ks * 32 + lk];
#pragma unroll
      for (int nt = 0; nt < 8; ++nt) {
        bf16x8 b = *(const bf16x8*)&Bsm[nt * 16 + lr][ks * 32 + lk];
        acc[nt] = mfma_bf16(b, a, acc[nt]);   // SWAPPED: C^T
      }
    }
    // acc[nt][r4] = C[row = local][ch = nt*16 + lkg*4 + r4]
    if (is_x0 || cb != 0) {
      f32x4 bias_v[8];
#pragma unroll
      for (int nt = 0; nt < 8; ++nt)
        bias_v[nt] = *(const f32x4*)&bias[cb * 128 + nt * 16 + lkg * 4];

      bf16_t* dst;
      if (is_x0) {
        int pix = pix0 + local;
        int rr = pix / 56, cc = pix - rr * 56;
        if (cb == 0) {
          int wn = b_ * 64 + (rr / 7) * 8 + cc / 7;
          int nidx = (rr % 7) * 7 + (cc % 7);
          dst = qout + (size_t)wn * 12544 + nidx * 128;
        } else {
          dst = (cb == 1 ? k0 : v0) + ((size_t)b_ * 3136 + pix) * CH;
        }
      } else {
        dst = (cb == 1 ? k1 : v1) + (size_t)(i1base + local) * CH;
      }
#pragma unroll
      for (int nt = 0; nt < 8; ++nt) {
        bf16x4 v;
#pragma unroll
        for (int r4 = 0; r4 < 4; ++r4)
          v[r4] = (bf16_t)(acc[nt][r4] + bias_v[nt][r4]);
        *(bf16x4*)&dst[nt * 16 + lkg * 4] = v;
      }
    }
    __syncthreads();                   // before restaging Bsm
  }
}

// ---------------------------------------------------------------------------
// K2: rpb MLP -> rpb_s = bf16(rpb * sqrt(32)) in thread-linear layout:
// elem(qh, row, m) = qh*8192 + ((row>>2)*16 + (m&15))*32 + (m>>4)*4 + (row&3)
// (row = q-row n, m = key col). Rows 49..63 left unwritten (per-row softmax
// isolation + guarded stores make garbage rows harmless, as in round-0).
// grid 1568 x 256 (n < 49 only).
// ---------------------------------------------------------------------------
__global__ __launch_bounds__(256) void k_rpb(
    const float* __restrict__ c0, const float* __restrict__ c1,
    const float* __restrict__ w10, const float* __restrict__ b10,
    const float* __restrict__ w20, const float* __restrict__ b20,
    const float* __restrict__ w11, const float* __restrict__ b11,
    const float* __restrict__ w21, const float* __restrict__ b21,
    bf16_t* __restrict__ rpb) {
  __shared__ float w1s[2][32][2], b1s[2][32], w2s[2][4][32], b2s[2][4];
  const int tid = threadIdx.x;
  if (tid < 64) {
    int s = tid >> 5, j = tid & 31;
    const float* w1p = s ? w11 : w10;
    const float* b1p = s ? b11 : b10;
    w1s[s][j][0] = w1p[j * 2];
    w1s[s][j][1] = w1p[j * 2 + 1];
    b1s[s][j] = b1p[j];
  }
  {
    int s = tid >> 7, rem = tid & 127, h = rem >> 5, j = rem & 31;
    w2s[s][h][j] = s ? w21[h * 32 + j] : w20[h * 32 + j];
  }
  if (tid < 8) {
    int s = tid >> 2, h = tid & 3;
    b2s[s][h] = s ? b21[h] : b20[h];
  }
  __syncthreads();

  int L = blockIdx.x * 256 + tid;      // < 64*49*128
  int m = L & 127;
  int n = (L >> 7) % WA;
  int qi = L / (128 * WA);
  int s = m >> 6, mi = m & 63;
  const float* cp = (s ? c1 : c0) + (((size_t)qi * WA + n) * 64 + mi) * 2;
  float cx = cp[0], cy = cp[1];
  float a0 = 0.f, a1 = 0.f, a2 = 0.f, a3 = 0.f;
#pragma unroll
  for (int j = 0; j < 32; ++j) {
    float h = fmaxf(w1s[s][j][0] * cx + w1s[s][j][1] * cy + b1s[s][j], 0.f);
    a0 += w2s[s][0][j] * h;
    a1 += w2s[s][1][j] * h;
    a2 += w2s[s][2][j] * h;
    a3 += w2s[s][3][j] * h;
  }
  size_t base = (size_t)(qi * 4) * 8192 +
                (size_t)(((n >> 2) * 16 + (m & 15)) * 32 + (m >> 4) * 4 + (n & 3));
  rpb[base]         = (bf16_t)((a0 + b2s[s][0]) * SQRT32);
  rpb[base + 8192]  = (bf16_t)((a1 + b2s[s][1]) * SQRT32);
  rpb[base + 16384] = (bf16_t)((a2 + b2s[s][2]) * SQRT32);
  rpb[base + 24576] = (bf16_t)((a3 + b2s[s][3]) * SQRT32);
}

// ---------------------------------------------------------------------------
// K3: attention. block = (b, qi, head-pair hp). 256 thr, 4 waves.
// (round-6 verified version, unchanged)
// ---------------------------------------------------------------------------
__global__ __launch_bounds__(256, 4) void k_attn(
    const bf16_t* qin,                  // d_out interleaved, aliased
    const bf16_t* __restrict__ k0, const bf16_t* __restrict__ v0,
    const bf16_t* __restrict__ k1, const bf16_t* __restrict__ v1,
    const int* __restrict__ idx0, const int* __restrict__ idx1,
    const bf16_t* __restrict__ rpb,
    float* attn_out) {                  // d_out, aliased
  __shared__ __align__(16) bf16_t Kt[128][72];   // [key][ch-in-pair] 18432B
  __shared__ __align__(16) bf16_t Vt[64][136];   // [ch-in-pair][key] 17408B
  bf16_t (*Sm)[136] = (bf16_t(*)[136])&Kt[0][0]; // P aliases Kt after barrier 2

  const int bid = blockIdx.x;          // 4096 = 32*64*2
  const int hp = bid & 1;
  const int qi = (bid >> 1) & 63;
  const int b = bid >> 7;
  const int tid = threadIdx.x;
  const int wn = b * 64 + qi;

  // ---- gather: key = lane-fastest => Vt scatter is 2-way (free)
#pragma unroll
  for (int i = 0; i < 4; ++i) {
    int uid = tid + 256 * i;           // 0..1023
    int key = uid & 127, seg = uid >> 7;
    size_t srcrow;
    const bf16_t *kbase, *vbase;
    if (key < 64) {
      srcrow = (size_t)b * 3136 + idx0[qi * 64 + key];
      kbase = k0; vbase = v0;
    } else {
      srcrow = (size_t)b * 64 + idx1[qi * 64 + key - 64];
      kbase = k1; vbase = v1;
    }
    size_t off = srcrow * CH + hp * 64 + seg * 8;
    *(uint4*)&Kt[key][seg * 8] = *(const uint4*)(kbase + off);
    union { uint4 u; bf16_t h[8]; } cv;
    cv.u = *(const uint4*)(vbase + off);
#pragma unroll
    for (int e = 0; e < 8; ++e) Vt[seg * 8 + e][key] = cv.h[e];
  }

  const int wid = tid >> 6, l = tid & 63;
  const int lr = l & 15, lkg = l >> 4, lk = lkg * 8;
  const int myrow = wid * 16 + lkg * 4;     // + r4
  int qr = wid * 16 + lr;
  if (qr > WA - 1) qr = WA - 1;

  // ---- preload BOTH heads' Q fragments before the barrier (alias safety)
  const bf16_t* qb = qin + (size_t)wn * 12544;
  bf16x8 qf[2];
  qf[0] = *(const bf16x8*)&qb[qr * 128 + hp * 64 + lk];
  qf[1] = *(const bf16x8*)&qb[qr * 128 + hp * 64 + 32 + lk];

  // ---- acc init = pre-scaled rpb (bf16 thread-linear: 4x uint4 per head),
  //      issued before the barrier so latency hides under the gather
  f32x4 acc[2][8];
#pragma unroll
  for (int lh = 0; lh < 2; ++lh) {
    const bf16_t* rp = rpb + (size_t)(qi * 4 + hp * 2 + lh) * 8192 +
                       (size_t)(((wid * 4 + lkg) * 16 + lr) * 32);
    union { uint4 u[4]; bf16_t h[32]; } rv;
#pragma unroll
    for (int i = 0; i < 4; ++i) rv.u[i] = *(const uint4*)(rp + i * 8);
#pragma unroll
    for (int nt = 0; nt < 8; ++nt)
#pragma unroll
      for (int r4 = 0; r4 < 4; ++r4)
        acc[lh][nt][r4] = (float)rv.h[nt * 4 + r4];
  }

  __syncthreads();                     // barrier 1: gather visible

  // ---- QK^T for both heads (Kt's last use)
#pragma unroll
  for (int lh = 0; lh < 2; ++lh)
#pragma unroll
    for (int nt = 0; nt < 8; ++nt) {
      bf16x8 bfr = *(const bf16x8*)&Kt[nt * 16 + lr][lh * 32 + lk];
      acc[lh][nt] = mfma_bf16(qf[lh], bfr, acc[lh][nt]);
    }

  __syncthreads();                     // barrier 2: Kt dead -> Sm may alias

  float* obase = attn_out + (size_t)wn * 6272;

#pragma unroll
  for (int lh = 0; lh < 2; ++lh) {
    const int hh = hp * 2 + lh;
    // ---- in-register softmax (rows live in fixed lanes)
    float mx[4] = {-1e30f, -1e30f, -1e30f, -1e30f};
#pragma unroll
    for (int nt = 0; nt < 8; ++nt)
#pragma unroll
      for (int r4 = 0; r4 < 4; ++r4) mx[r4] = fmaxf(mx[r4], acc[lh][nt][r4]);
#pragma unroll
    for (int m = 1; m < 16; m <<= 1)
#pragma unroll
      for (int r4 = 0; r4 < 4; ++r4)
        mx[r4] = fmaxf(mx[r4], __shfl_xor(mx[r4], m));
    float km[4];
#pragma unroll
    for (int r4 = 0; r4 < 4; ++r4) km[r4] = KE * mx[r4];
    float sum[4] = {0.f, 0.f, 0.f, 0.f};
#pragma unroll
    for (int nt = 0; nt < 8; ++nt)
#pragma unroll
      for (int r4 = 0; r4 < 4; ++r4) {
        float p = __builtin_amdgcn_exp2f(fmaf(KE, acc[lh][nt][r4], -km[r4]));
        acc[lh][nt][r4] = p;
        sum[r4] += p;
      }
#pragma unroll
    for (int m = 1; m < 16; m <<= 1)
#pragma unroll
      for (int r4 = 0; r4 < 4; ++r4) sum[r4] += __shfl_xor(sum[r4], m);
    float inv[4];
#pragma unroll
    for (int r4 = 0; r4 < 4; ++r4) inv[r4] = __builtin_amdgcn_rcpf(sum[r4]);
    // ---- P -> Sm (own rows only; same-wave WAR/RAW on LDS is in-order)
#pragma unroll
    for (int nt = 0; nt < 8; ++nt)
#pragma unroll
      for (int r4 = 0; r4 < 4; ++r4)
        Sm[myrow + r4][nt * 16 + lr] = (bf16_t)acc[lh][nt][r4];
    // no barrier: Sm rows wid*16..+15 written & read by this wave only
    f32x4 zero = {0.f, 0.f, 0.f, 0.f};
    f32x4 oacc[2];
    oacc[0] = zero; oacc[1] = zero;
#pragma unroll
    for (int ks = 0; ks < 4; ++ks) {
      bf16x8 pa = *(const bf16x8*)&Sm[wid * 16 + lr][ks * 32 + lk];
#pragma unroll
      for (int nt2 = 0; nt2 < 2; ++nt2) {
        bf16x8 vb = *(const bf16x8*)&Vt[lh * 32 + nt2 * 16 + lr][ks * 32 + lk];
        oacc[nt2] = mfma_bf16(pa, vb, oacc[nt2]);
      }
    }
#pragma unroll
    for (int nt2 = 0; nt2 < 2; ++nt2)
#pragma unroll
      for (int r4 = 0; r4 < 4; ++r4) {
        int rown = myrow + r4;
        if (rown < WA)
          obase[rown * 128 + hh * 32 + nt2 * 16 + lr] = oacc[nt2][r4] * inv[r4];
      }
  }
}

// ---------------------------------------------------------------------------
// K4: out = attn @ proj_w.T + proj_b, in place on d_out. grid 1568 x 256.
// B from pre-converted bf16 weights. MFMA operands SWAPPED: thread owns one
// output row, channels nt*16+lkg*4+{0..3} -> float4 stores.
// ---------------------------------------------------------------------------
__global__ __launch_bounds__(256) void k_proj(
    const float* attn,                  // aliases out
    const bf16_t* __restrict__ pw, const float* __restrict__ pb,
    float* out) {
  __shared__ __align__(16) bf16_t Asm[64][136];
  __shared__ __align__(16) bf16_t Bsm[128][136];
  const int rb = blockIdx.x;
  const int tid = threadIdx.x;
  const size_t row0 = (size_t)rb * 64;
#pragma unroll
  for (int i = 0; i < 4; ++i) {
    int uid = tid + 256 * i;
    int r = uid >> 4, cs = uid & 15;
    *(bf16x8*)&Asm[r][cs * 8] = cvt8(attn + (row0 + r) * CH + cs * 8);
  }
#pragma unroll
  for (int i = 0; i < 8; ++i) {
    int uid = tid + 256 * i;
    int r = uid >> 4, cs = uid & 15;
    *(uint4*)&Bsm[r][cs * 8] = *(const uint4*)(pw + (size_t)r * CH + cs * 8);
  }
  __syncthreads();

  const int wid = tid >> 6, l = tid & 63;
  const int lr = l & 15, lkg = l >> 4, lk = lkg * 8;
  f32x4 zero = {0.f, 0.f, 0.f, 0.f};
  f32x4 acc[8];
#pragma unroll
  for (int nt = 0; nt < 8; ++nt) acc[nt] = zero;
#pragma unroll
  for (int ks = 0; ks < 4; ++ks) {
    bf16x8 a = *(const bf16x8*)&Asm[wid * 16 + lr][ks * 32 + lk];
#pragma unroll
    for (int nt = 0; nt < 8; ++nt) {
      bf16x8 b = *(const bf16x8*)&Bsm[nt * 16 + lr][ks * 32 + lk];
      acc[nt] = mfma_bf16(b, a, acc[nt]);   // SWAPPED: C^T
    }
  }
  // acc[nt][r4] = C[row = wid*16+lr][ch = nt*16 + lkg*4 + r4]
  const size_t g = row0 + (size_t)(wid * 16 + lr);
#pragma unroll
  for (int nt = 0; nt < 8; ++nt) {
    f32x4 bv = *(const f32x4*)&pb[nt * 16 + lkg * 4];
    f32x4 v;
#pragma unroll
    for (int r4 = 0; r4 < 4; ++r4) v[r4] = acc[nt][r4] + bv[r4];
    *(f32x4*)&out[g * CH + nt * 16 + lkg * 4] = v;
  }
}

// ---------------------------------------------------------------------------
// launch
// ---------------------------------------------------------------------------
extern "C" void kernel_launch(void* const* d_in, const int* in_sizes, int n_in,
                              void* d_out, int out_size, void* d_ws, size_t ws_size,
                              hipStream_t stream) {
  const float* x0 = (const float*)d_in[0];
  const float* x1 = (const float*)d_in[1];
  const float* qkv_w = (const float*)d_in[2];
  const float* qkv_b = (const float*)d_in[3];
  const float* proj_w = (const float*)d_in[4];
  const float* proj_b = (const float*)d_in[5];
  const float* rpb0_w1 = (const float*)d_in[6];
  const float* rpb0_b1 = (const float*)d_in[7];
  const float* rpb0_w2 = (const float*)d_in[8];
  const float* rpb0_b2 = (const float*)d_in[9];
  const float* rpb1_w1 = (const float*)d_in[10];
  const float* rpb1_b1 = (const float*)d_in[11];
  const float* rpb1_w2 = (const float*)d_in[12];
  const float* rpb1_b2 = (const float*)d_in[13];
  const float* coords0 = (const float*)d_in[14];
  const float* coords1 = (const float*)d_in[15];
  const int* idx0 = (const int*)d_in[16];
  const int* idx1 = (const int*)d_in[17];

  // workspace: 56.75 MB
  char* ws = (char*)d_ws;
  bf16_t* k0 = (bf16_t*)(ws + 0);               // 25,690,112
  bf16_t* v0 = (bf16_t*)(ws + 25690112);        // 25,690,112
  bf16_t* k1 = (bf16_t*)(ws + 51380224);        //    524,288
  bf16_t* v1 = (bf16_t*)(ws + 51904512);        //    524,288
  bf16_t* rpb = (bf16_t*)(ws + 52428800);       //  4,194,304 (bf16 thread-lin)
  bf16_t* wq = (bf16_t*)(ws + 56623104);        //     98,304
  bf16_t* wp = (bf16_t*)(ws + 56721408);        //     32,768

  k_prep<<<32, 256, 0, stream>>>(qkv_w, proj_w, wq, wp);
  k_qkv<<<1600, 256, 0, stream>>>(x0, x1, wq, qkv_b,
                                  (bf16_t*)d_out, k0, v0, k1, v1);
  k_rpb<<<1568, 256, 0, stream>>>(coords0, coords1, rpb0_w1, rpb0_b1, rpb0_w2,
                                  rpb0_b2, rpb1_w1, rpb1_b1, rpb1_w2, rpb1_b2,
                                  rpb);
  k_attn<<<4096, 256, 0, stream>>>((const bf16_t*)d_out, k0, v0, k1, v1,
                                   idx0, idx1, rpb, (float*)d_out);
  k_proj<<<1568, 256, 0, stream>>>((const float*)d_out, wp, proj_b,
                                   (float*)d_out);
}

// Round 8
// 216.272 us; speedup vs baseline: 1.0863x; 1.0863x over previous
//
#include <hip/hip_runtime.h>
#include <hip/hip_bf16.h>

// ---------------------------------------------------------------------------
// WindowAttention: B=32 RES=56 C=128 HEADS=4 HD=32 WS=7 NW=8 NQ=64 WA=49
// 128 keys/window (64 gathered full-res + 64 x1-level). fp32 I/O, bf16 MFMA.
// Round-6 verified structure (round-7 operand swap reverted: lane-major
// scalar-store epilogues coalesce better than thread-major vector stores).
// Deltas this round:
//  (1) O crosses k_attn -> k_proj as BF16, element-aliased in d_out: O row g
//      lives at bf16-index g*256 (first 256B of the final fp32 row slot).
//      Halves attn write bytes + proj read bytes; removes proj's A cvts.
//      k_proj stays element-wise in-place (read [g*512,+256) within write
//      [g*512,+512)) -> race-free. attn's O-stores clobber only the q
//      elements its own hp reads (hp0: ch0-63, hp1: ch64-127) -> removes the
//      round-6 cross-hp q timing exposure.
//  (2) k_prep folded into k_rpb (blocks 1568-1599), launched first.
// Buffer plan:
//   d_out: per-window interleaved — q (bf16, first 12544B of each 25088B
//   window slot) -> k_attn writes bf16 O at row-aliased offsets -> k_proj
//   in-place fp32 final.
//   d_ws 56.75MB: k0,v0,k1,v1 (bf16) + rpb (bf16 thread-linear, pre-scaled
//   sqrt(32)) + wq_bf16 + wp_bf16.
// ---------------------------------------------------------------------------

typedef __bf16 bf16_t;
typedef __bf16 bf16x8 __attribute__((ext_vector_type(8)));
typedef float f32x4 __attribute__((ext_vector_type(4)));

static __device__ __forceinline__ f32x4 mfma_bf16(bf16x8 a, bf16x8 b, f32x4 c) {
  return __builtin_amdgcn_mfma_f32_16x16x32_bf16(a, b, c, 0, 0, 0);
}

static __device__ __forceinline__ bf16x8 cvt8(const float* __restrict__ p) {
  float4 a = *(const float4*)p;
  float4 b = *(const float4*)(p + 4);
  bf16x8 r;
  r[0] = (bf16_t)a.x; r[1] = (bf16_t)a.y; r[2] = (bf16_t)a.z; r[3] = (bf16_t)a.w;
  r[4] = (bf16_t)b.x; r[5] = (bf16_t)b.y; r[6] = (bf16_t)b.z; r[7] = (bf16_t)b.w;
  return r;
}

#define NB 32
#define RES 56
#define CH 128
#define NW 8
#define NQ 64
#define WA 49
#define X0_ROWS (NB * RES * RES)       // 100352
#define SCALE 0.17677669529663687f     // 32^-0.5
#define SQRT32 5.656854249492381f
#define KE 0.25503164508761f           // SCALE * log2(e)

// ---------------------------------------------------------------------------
// K1: qkv GEMM, A staged once, cb=q/k/v looped in-block. grid 1600 x 256.
// B staged from pre-converted bf16 weights. (round-6 verified version)
// ---------------------------------------------------------------------------
__global__ __launch_bounds__(256) void k_qkv(
    const float* __restrict__ x0, const float* __restrict__ x1,
    const bf16_t* __restrict__ w, const float* __restrict__ bias,
    bf16_t* __restrict__ qout,          // d_out, interleaved windows
    bf16_t* __restrict__ k0, bf16_t* __restrict__ v0,
    bf16_t* __restrict__ k1, bf16_t* __restrict__ v1) {
  __shared__ __align__(16) bf16_t Asm[64][136];
  __shared__ __align__(16) bf16_t Bsm[128][136];
  const int rb = blockIdx.x;           // 0..1599 (>=1568: x1 rows)
  const int tid = threadIdx.x;
  const size_t row0 = (size_t)rb * 64;
  const bool is_x0 = (rb < 1568);
  const int b_ = rb / 49;              // 3136 = 49*64: block never crosses batch
  const int pix0 = (rb - b_ * 49) * 64;
  const int i1base = (rb - 1568) * 64;

  const float* src = is_x0 ? (x0 + row0 * CH)
                           : (x1 + (row0 - X0_ROWS) * CH);
#pragma unroll
  for (int i = 0; i < 4; ++i) {        // A: 64x128
    int uid = tid + 256 * i;
    int r = uid >> 4, cs = uid & 15;
    *(bf16x8*)&Asm[r][cs * 8] = cvt8(src + (size_t)r * CH + cs * 8);
  }

  const int wid = tid >> 6, l = tid & 63;
  const int lr = l & 15, lkg = l >> 4, lk = lkg * 8;

  for (int cb = 0; cb < 3; ++cb) {
    const bf16_t* wsrc = w + (size_t)cb * 128 * CH;
#pragma unroll
    for (int i = 0; i < 8; ++i) {      // B: 128x128 (bf16 copy, no cvt)
      int uid = tid + 256 * i;
      int r = uid >> 4, cs = uid & 15;
      *(uint4*)&Bsm[r][cs * 8] = *(const uint4*)(wsrc + (size_t)r * CH + cs * 8);
    }
    __syncthreads();

    f32x4 zero = {0.f, 0.f, 0.f, 0.f};
    f32x4 acc[8];
#pragma unroll
    for (int nt = 0; nt < 8; ++nt) acc[nt] = zero;
#pragma unroll
    for (int ks = 0; ks < 4; ++ks) {
      bf16x8 a = *(const bf16x8*)&Asm[wid * 16 + lr][ks * 32 + lk];
#pragma unroll
      for (int nt = 0; nt < 8; ++nt) {
        bf16x8 b = *(const bf16x8*)&Bsm[nt * 16 + lr][ks * 32 + lk];
        acc[nt] = mfma_bf16(a, b, acc[nt]);
      }
    }
    float bias_v[8];
#pragma unroll
    for (int nt = 0; nt < 8; ++nt) bias_v[nt] = bias[cb * 128 + nt * 16 + lr];

#pragma unroll
    for (int r4 = 0; r4 < 4; ++r4) {
      int local = wid * 16 + lkg * 4 + r4;
      if (is_x0) {
        int pix = pix0 + local;
        int rr = pix / 56, cc = pix - rr * 56;
        if (cb == 0) {
          int wn = b_ * 64 + (rr / 7) * 8 + cc / 7;
          int nidx = (rr % 7) * 7 + (cc % 7);
          bf16_t* dst = qout + (size_t)wn * 12544 + nidx * 128;
#pragma unroll
          for (int nt = 0; nt < 8; ++nt)
            dst[nt * 16 + lr] = (bf16_t)(acc[nt][r4] + bias_v[nt]);
        } else {
          bf16_t* dst = (cb == 1 ? k0 : v0) +
                        ((size_t)b_ * 3136 + pix) * CH;
#pragma unroll
          for (int nt = 0; nt < 8; ++nt)
            dst[nt * 16 + lr] = (bf16_t)(acc[nt][r4] + bias_v[nt]);
        }
      } else if (cb != 0) {
        bf16_t* dst = (cb == 1 ? k1 : v1) + (size_t)(i1base + local) * CH;
#pragma unroll
        for (int nt = 0; nt < 8; ++nt)
          dst[nt * 16 + lr] = (bf16_t)(acc[nt][r4] + bias_v[nt]);
      }
    }
    __syncthreads();                   // before restaging Bsm
  }
}

// ---------------------------------------------------------------------------
// K2: rpb MLP (blocks < 1568) + weight pre-convert (blocks 1568..1599).
// rpb_s = bf16(rpb * sqrt(32)) in thread-linear layout:
// elem(qh, row, m) = qh*8192 + ((row>>2)*16 + (m&15))*32 + (m>>4)*4 + (row&3)
// Rows 49..63 left unwritten (per-row softmax isolation + guarded stores).
// grid 1600 x 256.
// ---------------------------------------------------------------------------
__global__ __launch_bounds__(256) void k_rpb(
    const float* __restrict__ c0, const float* __restrict__ c1,
    const float* __restrict__ w10, const float* __restrict__ b10,
    const float* __restrict__ w20, const float* __restrict__ b20,
    const float* __restrict__ w11, const float* __restrict__ b11,
    const float* __restrict__ w21, const float* __restrict__ b21,
    bf16_t* __restrict__ rpb,
    const float* __restrict__ qw, const float* __restrict__ pw,
    bf16_t* __restrict__ wq, bf16_t* __restrict__ wp) {
  const int tid = threadIdx.x;
  if (blockIdx.x >= 1568) {            // fused k_prep
    int i = ((blockIdx.x - 1568) * 256 + tid) * 8;
    if (i < 49152) {
      *(bf16x8*)&wq[i] = cvt8(qw + i);
    } else {
      int j = i - 49152;
      *(bf16x8*)&wp[j] = cvt8(pw + j);
    }
    return;
  }

  __shared__ float w1s[2][32][2], b1s[2][32], w2s[2][4][32], b2s[2][4];
  if (tid < 64) {
    int s = tid >> 5, j = tid & 31;
    const float* w1p = s ? w11 : w10;
    const float* b1p = s ? b11 : b10;
    w1s[s][j][0] = w1p[j * 2];
    w1s[s][j][1] = w1p[j * 2 + 1];
    b1s[s][j] = b1p[j];
  }
  {
    int s = tid >> 7, rem = tid & 127, h = rem >> 5, j = rem & 31;
    w2s[s][h][j] = s ? w21[h * 32 + j] : w20[h * 32 + j];
  }
  if (tid < 8) {
    int s = tid >> 2, h = tid & 3;
    b2s[s][h] = s ? b21[h] : b20[h];
  }
  __syncthreads();

  int L = blockIdx.x * 256 + tid;      // < 64*49*128
  int m = L & 127;
  int n = (L >> 7) % WA;
  int qi = L / (128 * WA);
  int s = m >> 6, mi = m & 63;
  const float* cp = (s ? c1 : c0) + (((size_t)qi * WA + n) * 64 + mi) * 2;
  float cx = cp[0], cy = cp[1];
  float a0 = 0.f, a1 = 0.f, a2 = 0.f, a3 = 0.f;
#pragma unroll
  for (int j = 0; j < 32; ++j) {
    float h = fmaxf(w1s[s][j][0] * cx + w1s[s][j][1] * cy + b1s[s][j], 0.f);
    a0 += w2s[s][0][j] * h;
    a1 += w2s[s][1][j] * h;
    a2 += w2s[s][2][j] * h;
    a3 += w2s[s][3][j] * h;
  }
  size_t base = (size_t)(qi * 4) * 8192 +
                (size_t)(((n >> 2) * 16 + (m & 15)) * 32 + (m >> 4) * 4 + (n & 3));
  rpb[base]         = (bf16_t)((a0 + b2s[s][0]) * SQRT32);
  rpb[base + 8192]  = (bf16_t)((a1 + b2s[s][1]) * SQRT32);
  rpb[base + 16384] = (bf16_t)((a2 + b2s[s][2]) * SQRT32);
  rpb[base + 24576] = (bf16_t)((a3 + b2s[s][3]) * SQRT32);
}

// ---------------------------------------------------------------------------
// K3: attention. block = (b, qi, head-pair hp). 256 thr, 4 waves.
// Round-6 verified structure; only the O store changed: bf16, element-
// aliased at bf16-index (wn*49+rown)*256 + ch. Each hp clobbers only the
// q elements it itself preloads (hp0: ch0-63, hp1: ch64-127).
// ---------------------------------------------------------------------------
__global__ __launch_bounds__(256, 4) void k_attn(
    const bf16_t* qin,                  // d_out interleaved, aliased
    const bf16_t* __restrict__ k0, const bf16_t* __restrict__ v0,
    const bf16_t* __restrict__ k1, const bf16_t* __restrict__ v1,
    const int* __restrict__ idx0, const int* __restrict__ idx1,
    const bf16_t* __restrict__ rpb,
    bf16_t* attn_out) {                 // d_out as bf16, aliased
  __shared__ __align__(16) bf16_t Kt[128][72];   // [key][ch-in-pair] 18432B
  __shared__ __align__(16) bf16_t Vt[64][136];   // [ch-in-pair][key] 17408B
  bf16_t (*Sm)[136] = (bf16_t(*)[136])&Kt[0][0]; // P aliases Kt after barrier 2

  const int bid = blockIdx.x;          // 4096 = 32*64*2
  const int hp = bid & 1;
  const int qi = (bid >> 1) & 63;
  const int b = bid >> 7;
  const int tid = threadIdx.x;
  const int wn = b * 64 + qi;

  // ---- gather: key = lane-fastest => Vt scatter is 2-way (free)
#pragma unroll
  for (int i = 0; i < 4; ++i) {
    int uid = tid + 256 * i;           // 0..1023
    int key = uid & 127, seg = uid >> 7;
    size_t srcrow;
    const bf16_t *kbase, *vbase;
    if (key < 64) {
      srcrow = (size_t)b * 3136 + idx0[qi * 64 + key];
      kbase = k0; vbase = v0;
    } else {
      srcrow = (size_t)b * 64 + idx1[qi * 64 + key - 64];
      kbase = k1; vbase = v1;
    }
    size_t off = srcrow * CH + hp * 64 + seg * 8;
    *(uint4*)&Kt[key][seg * 8] = *(const uint4*)(kbase + off);
    union { uint4 u; bf16_t h[8]; } cv;
    cv.u = *(const uint4*)(vbase + off);
#pragma unroll
    for (int e = 0; e < 8; ++e) Vt[seg * 8 + e][key] = cv.h[e];
  }

  const int wid = tid >> 6, l = tid & 63;
  const int lr = l & 15, lkg = l >> 4, lk = lkg * 8;
  const int myrow = wid * 16 + lkg * 4;     // + r4
  int qr = wid * 16 + lr;
  if (qr > WA - 1) qr = WA - 1;

  // ---- preload BOTH heads' Q fragments before the barrier (alias safety)
  const bf16_t* qb = qin + (size_t)wn * 12544;
  bf16x8 qf[2];
  qf[0] = *(const bf16x8*)&qb[qr * 128 + hp * 64 + lk];
  qf[1] = *(const bf16x8*)&qb[qr * 128 + hp * 64 + 32 + lk];

  // ---- acc init = pre-scaled rpb (bf16 thread-linear: 4x uint4 per head),
  //      issued before the barrier so latency hides under the gather
  f32x4 acc[2][8];
#pragma unroll
  for (int lh = 0; lh < 2; ++lh) {
    const bf16_t* rp = rpb + (size_t)(qi * 4 + hp * 2 + lh) * 8192 +
                       (size_t)(((wid * 4 + lkg) * 16 + lr) * 32);
    union { uint4 u[4]; bf16_t h[32]; } rv;
#pragma unroll
    for (int i = 0; i < 4; ++i) rv.u[i] = *(const uint4*)(rp + i * 8);
#pragma unroll
    for (int nt = 0; nt < 8; ++nt)
#pragma unroll
      for (int r4 = 0; r4 < 4; ++r4)
        acc[lh][nt][r4] = (float)rv.h[nt * 4 + r4];
  }

  __syncthreads();                     // barrier 1: gather visible

  // ---- QK^T for both heads (Kt's last use)
#pragma unroll
  for (int lh = 0; lh < 2; ++lh)
#pragma unroll
    for (int nt = 0; nt < 8; ++nt) {
      bf16x8 bfr = *(const bf16x8*)&Kt[nt * 16 + lr][lh * 32 + lk];
      acc[lh][nt] = mfma_bf16(qf[lh], bfr, acc[lh][nt]);
    }

  __syncthreads();                     // barrier 2: Kt dead -> Sm may alias

  bf16_t* obase = attn_out + (size_t)wn * 49 * 256;  // O row g at g*256

#pragma unroll
  for (int lh = 0; lh < 2; ++lh) {
    const int hh = hp * 2 + lh;
    // ---- in-register softmax (rows live in fixed lanes)
    float mx[4] = {-1e30f, -1e30f, -1e30f, -1e30f};
#pragma unroll
    for (int nt = 0; nt < 8; ++nt)
#pragma unroll
      for (int r4 = 0; r4 < 4; ++r4) mx[r4] = fmaxf(mx[r4], acc[lh][nt][r4]);
#pragma unroll
    for (int m = 1; m < 16; m <<= 1)
#pragma unroll
      for (int r4 = 0; r4 < 4; ++r4)
        mx[r4] = fmaxf(mx[r4], __shfl_xor(mx[r4], m));
    float km[4];
#pragma unroll
    for (int r4 = 0; r4 < 4; ++r4) km[r4] = KE * mx[r4];
    float sum[4] = {0.f, 0.f, 0.f, 0.f};
#pragma unroll
    for (int nt = 0; nt < 8; ++nt)
#pragma unroll
      for (int r4 = 0; r4 < 4; ++r4) {
        float p = __builtin_amdgcn_exp2f(fmaf(KE, acc[lh][nt][r4], -km[r4]));
        acc[lh][nt][r4] = p;
        sum[r4] += p;
      }
#pragma unroll
    for (int m = 1; m < 16; m <<= 1)
#pragma unroll
      for (int r4 = 0; r4 < 4; ++r4) sum[r4] += __shfl_xor(sum[r4], m);
    float inv[4];
#pragma unroll
    for (int r4 = 0; r4 < 4; ++r4) inv[r4] = __builtin_amdgcn_rcpf(sum[r4]);
    // ---- P -> Sm (own rows only; same-wave WAR/RAW on LDS is in-order)
#pragma unroll
    for (int nt = 0; nt < 8; ++nt)
#pragma unroll
      for (int r4 = 0; r4 < 4; ++r4)
        Sm[myrow + r4][nt * 16 + lr] = (bf16_t)acc[lh][nt][r4];
    // no barrier: Sm rows wid*16..+15 written & read by this wave only
    f32x4 zero = {0.f, 0.f, 0.f, 0.f};
    f32x4 oacc[2];
    oacc[0] = zero; oacc[1] = zero;
#pragma unroll
    for (int ks = 0; ks < 4; ++ks) {
      bf16x8 pa = *(const bf16x8*)&Sm[wid * 16 + lr][ks * 32 + lk];
#pragma unroll
      for (int nt2 = 0; nt2 < 2; ++nt2) {
        bf16x8 vb = *(const bf16x8*)&Vt[lh * 32 + nt2 * 16 + lr][ks * 32 + lk];
        oacc[nt2] = mfma_bf16(pa, vb, oacc[nt2]);
      }
    }
#pragma unroll
    for (int nt2 = 0; nt2 < 2; ++nt2)
#pragma unroll
      for (int r4 = 0; r4 < 4; ++r4) {
        int rown = myrow + r4;
        if (rown < WA)
          obase[(size_t)rown * 256 + hh * 32 + nt2 * 16 + lr] =
              (bf16_t)(oacc[nt2][r4] * inv[r4]);
      }
  }
}

// ---------------------------------------------------------------------------
// K4: out = attn @ proj_w.T + proj_b, in place on d_out. grid 1568 x 256.
// A staged from bf16 O at bf16-index g*256 (no cvt); element-wise in-place
// (read [g*512,+256) within write [g*512,+512)). (round-6 epilogue)
// ---------------------------------------------------------------------------
__global__ __launch_bounds__(256) void k_proj(
    const bf16_t* attn,                 // d_out as bf16, aliases out
    const bf16_t* __restrict__ pw, const float* __restrict__ pb,
    float* out) {
  __shared__ __align__(16) bf16_t Asm[64][136];
  __shared__ __align__(16) bf16_t Bsm[128][136];
  const int rb = blockIdx.x;
  const int tid = threadIdx.x;
  const size_t row0 = (size_t)rb * 64;
#pragma unroll
  for (int i = 0; i < 4; ++i) {
    int uid = tid + 256 * i;
    int r = uid >> 4, cs = uid & 15;
    *(uint4*)&Asm[r][cs * 8] =
        *(const uint4*)(attn + (row0 + r) * 256 + cs * 8);
  }
#pragma unroll
  for (int i = 0; i < 8; ++i) {
    int uid = tid + 256 * i;
    int r = uid >> 4, cs = uid & 15;
    *(uint4*)&Bsm[r][cs * 8] = *(const uint4*)(pw + (size_t)r * CH + cs * 8);
  }
  __syncthreads();

  const int wid = tid >> 6, l = tid & 63;
  const int lr = l & 15, lkg = l >> 4, lk = lkg * 8;
  f32x4 zero = {0.f, 0.f, 0.f, 0.f};
  f32x4 acc[8];
#pragma unroll
  for (int nt = 0; nt < 8; ++nt) acc[nt] = zero;
#pragma unroll
  for (int ks = 0; ks < 4; ++ks) {
    bf16x8 a = *(const bf16x8*)&Asm[wid * 16 + lr][ks * 32 + lk];
#pragma unroll
    for (int nt = 0; nt < 8; ++nt) {
      bf16x8 b = *(const bf16x8*)&Bsm[nt * 16 + lr][ks * 32 + lk];
      acc[nt] = mfma_bf16(a, b, acc[nt]);
    }
  }
#pragma unroll
  for (int nt = 0; nt < 8; ++nt) {
    int n = nt * 16 + lr;
    float bs = pb[n];
#pragma unroll
    for (int r4 = 0; r4 < 4; ++r4) {
      size_t g = row0 + (size_t)(wid * 16 + lkg * 4 + r4);
      out[g * CH + n] = acc[nt][r4] + bs;
    }
  }
}

// ---------------------------------------------------------------------------
// launch
// ---------------------------------------------------------------------------
extern "C" void kernel_launch(void* const* d_in, const int* in_sizes, int n_in,
                              void* d_out, int out_size, void* d_ws, size_t ws_size,
                              hipStream_t stream) {
  const float* x0 = (const float*)d_in[0];
  const float* x1 = (const float*)d_in[1];
  const float* qkv_w = (const float*)d_in[2];
  const float* qkv_b = (const float*)d_in[3];
  const float* proj_w = (const float*)d_in[4];
  const float* proj_b = (const float*)d_in[5];
  const float* rpb0_w1 = (const float*)d_in[6];
  const float* rpb0_b1 = (const float*)d_in[7];
  const float* rpb0_w2 = (const float*)d_in[8];
  const float* rpb0_b2 = (const float*)d_in[9];
  const float* rpb1_w1 = (const float*)d_in[10];
  const float* rpb1_b1 = (const float*)d_in[11];
  const float* rpb1_w2 = (const float*)d_in[12];
  const float* rpb1_b2 = (const float*)d_in[13];
  const float* coords0 = (const float*)d_in[14];
  const float* coords1 = (const float*)d_in[15];
  const int* idx0 = (const int*)d_in[16];
  const int* idx1 = (const int*)d_in[17];

  // workspace: 56.75 MB
  char* ws = (char*)d_ws;
  bf16_t* k0 = (bf16_t*)(ws + 0);               // 25,690,112
  bf16_t* v0 = (bf16_t*)(ws + 25690112);        // 25,690,112
  bf16_t* k1 = (bf16_t*)(ws + 51380224);        //    524,288
  bf16_t* v1 = (bf16_t*)(ws + 51904512);        //    524,288
  bf16_t* rpb = (bf16_t*)(ws + 52428800);       //  4,194,304 (bf16 thread-lin)
  bf16_t* wq = (bf16_t*)(ws + 56623104);        //     98,304
  bf16_t* wp = (bf16_t*)(ws + 56721408);        //     32,768

  k_rpb<<<1600, 256, 0, stream>>>(coords0, coords1, rpb0_w1, rpb0_b1, rpb0_w2,
                                  rpb0_b2, rpb1_w1, rpb1_b1, rpb1_w2, rpb1_b2,
                                  rpb, qkv_w, proj_w, wq, wp);
  k_qkv<<<1600, 256, 0, stream>>>(x0, x1, wq, qkv_b,
                                  (bf16_t*)d_out, k0, v0, k1, v1);
  k_attn<<<4096, 256, 0, stream>>>((const bf16_t*)d_out, k0, v0, k1, v1,
                                   idx0, idx1, rpb, (bf16_t*)d_out);
  k_proj<<<1568, 256, 0, stream>>>((const bf16_t*)d_out, wp, proj_b,
                                   (float*)d_out);
}